// Round 4
// baseline (21893.004 us; speedup 1.0000x reference)
//
#include <hip/hip_runtime.h>
#include <math.h>

#define H 256
#define H4 1024
#define Bsz 1024
#define TIN 168
#define TOUT 24
#define Fh 8
#define XROW (TIN*Fh)
#define BH ((size_t)Bsz * H)   // 262144
#define NWG 512

typedef __attribute__((ext_vector_type(8))) short bf16x8;
typedef __attribute__((ext_vector_type(4))) float f32x4;

__device__ __forceinline__ float sigmf(float x) { return 1.0f / (1.0f + expf(-x)); }

__device__ __forceinline__ ushort f2bf(float f) {
    union { float f; unsigned u; } v; v.f = f;
    unsigned r = v.u + 0x7fff + ((v.u >> 16) & 1);
    return (ushort)(r >> 16);
}
__device__ __forceinline__ float bf2f(ushort u) {
    union { unsigned u; float f; } v; v.u = ((unsigned)u) << 16;
    return v.f;
}

__global__ __launch_bounds__(256)
void cast_f32_bf16(const float* __restrict__ in, ushort* __restrict__ out, int n) {
    int i = blockIdx.x * 256 + threadIdx.x;
    const int stride = gridDim.x * 256;
    for (; i < n; i += stride) out[i] = f2bf(in[i]);
}

// Precompute (once): w[f]=f2W@oW; u[f]=inW_v^T@w; d[f]=inb_v.w; cc[f]=ob.f2W+f2b
__global__ __launch_bounds__(256)
void precompute_kernel(const float* __restrict__ oW, const float* __restrict__ ob,
                       const float* __restrict__ f2W, const float* __restrict__ f2b,
                       const float* __restrict__ inW, const float* __restrict__ inb,
                       float* __restrict__ u, float* __restrict__ dconst,
                       float* __restrict__ ccv)
{
    __shared__ float wsh[256];
    const int f = blockIdx.x;
    const int tid = threadIdx.x;
    float s = 0.f;
    for (int i = 0; i < 256; ++i)
        s += f2W[f * 256 + i] * oW[(size_t)f * 65536 + (size_t)i * 256 + tid];
    wsh[tid] = s;
    __syncthreads();
    float su = 0.f;
    for (int n = 0; n < 256; ++n)
        su += wsh[n] * inW[(size_t)f * 768 * 256 + (size_t)(512 + n) * 256 + tid];
    u[f * 256 + tid] = su;
    if (tid == 0) {
        float dd = 0.f, cc = 0.f;
        for (int n = 0; n < 256; ++n) dd += wsh[n] * inb[f * 768 + 512 + n];
        for (int i = 0; i < 256; ++i) cc += ob[f * 256 + i] * f2W[f * 256 + i];
        dconst[f] = dd;
        ccv[f] = cc + f2b[f];
    }
}

// ---------------- mega-kernel params ----------------
struct MP {
    const float *x, *eWih0, *ebih0, *ebhh0, *ebih1, *ebhh1;
    const ushort *wWhh0, *wWih1, *wWhh1;
    const float *dWih, *dbih, *dbhh, *f1b, *inb;
    const ushort *wdWhh, *wf1W, *winW;
    const float *u, *dconst, *ccv;
    float *c0, *c1, *dc, *vw, *din, *out;
    ushort *h0a, *h1a, *h0b, *h1b, *dh0, *dh1, *qbuf, *kbuf;
    unsigned *bar;
};

// grid barrier: monotonic counter, release/acquire device-scope
__device__ __forceinline__ void gbar(unsigned* bar, unsigned target) {
    __syncthreads();
    if (threadIdx.x == 0) {
        __threadfence();
        __hip_atomic_fetch_add(bar, 1u, __ATOMIC_RELEASE, __HIP_MEMORY_SCOPE_AGENT);
        while (__hip_atomic_load(bar, __ATOMIC_ACQUIRE, __HIP_MEMORY_SCOPE_AGENT) < target)
            __builtin_amdgcn_s_sleep(2);
        __threadfence();
    }
    __syncthreads();
}

// ---------------- encoder phase (verbatim body, re-gridded) ----------------
__device__ void enc_phase(const MP& P, int wg, int t)
{
    const int z = wg >> 8;
    if (z == 0 && t >= TIN) return;
    if (z == 1 && t < 1) return;
    const int bx = wg & 15, by = (wg >> 4) & 15;
    const int p = t & 1;
    const ushort* h0in = p ? P.h0b : P.h0a;
    ushort*       h0out = p ? P.h0a : P.h0b;
    const ushort* h1in = p ? P.h1a : P.h1b;
    ushort*       h1out = p ? P.h1b : P.h1a;

    const int tid = threadIdx.x;
    const int l = tid & 63, w = tid >> 6;
    const int m0 = bx * 64 + w * 16;
    const int jj0 = by * 16;
    const int lr = l & 15, lk = (l >> 4) * 8;

    const ushort* Ap  = (z == 0) ? h0in : h1in;
    const ushort* Wp  = (z == 0) ? P.wWhh0 : P.wWhh1;
    const float* bih  = (z == 0) ? P.ebih0 : P.ebih1;
    const float* bhh  = (z == 0) ? P.ebhh0 : P.ebhh1;
    float* cb         = (z == 0) ? P.c0 : P.c1;
    ushort* hout      = (z == 0) ? h0out : h1out;

    f32x4 acc[4] = {};
    {
        const ushort* Arow = Ap + (size_t)(m0 + lr) * H + lk;
        const ushort* Wrow = Wp + (size_t)(jj0 + lr) * H + lk;
        for (int ks = 0; ks < H; ks += 32) {
            bf16x8 af = *(const bf16x8*)(Arow + ks);
#pragma unroll
            for (int g = 0; g < 4; ++g) {
                bf16x8 bf = *(const bf16x8*)(Wrow + (size_t)g * (H * H) + ks);
                acc[g] = __builtin_amdgcn_mfma_f32_16x16x32_bf16(af, bf, acc[g], 0, 0, 0);
            }
        }
    }
    if (z == 1) {  // + ys0[t-1] @ Wih1^T
        const ushort* Arow = h0in + (size_t)(m0 + lr) * H + lk;
        const ushort* Wrow = P.wWih1 + (size_t)(jj0 + lr) * H + lk;
        for (int ks = 0; ks < H; ks += 32) {
            bf16x8 af = *(const bf16x8*)(Arow + ks);
#pragma unroll
            for (int g = 0; g < 4; ++g) {
                bf16x8 bf = *(const bf16x8*)(Wrow + (size_t)g * (H * H) + ks);
                acc[g] = __builtin_amdgcn_mfma_f32_16x16x32_bf16(af, bf, acc[g], 0, 0, 0);
            }
        }
    }

    const int jj = jj0 + lr;
    const int mb = m0 + (l >> 4) * 4;
#pragma unroll
    for (int r = 0; r < 4; ++r) {
        const int m = mb + r;
        float pre[4];
#pragma unroll
        for (int g = 0; g < 4; ++g)
            pre[g] = acc[g][r] + bih[g * H + jj] + bhh[g * H + jj];
        if (z == 0) {
            const float* xr = P.x + (size_t)m * XROW + t * Fh;
#pragma unroll
            for (int g = 0; g < 4; ++g) {
                const float* wr = P.eWih0 + (size_t)(g * H + jj) * Fh;
                float s = 0.f;
#pragma unroll
                for (int ki = 0; ki < Fh; ++ki) s = fmaf(xr[ki], wr[ki], s);
                pre[g] += s;
            }
        }
        const float ig = sigmf(pre[0]);
        const float fg = sigmf(pre[1]);
        const float gg = tanhf(pre[2]);
        const float og = sigmf(pre[3]);
        const size_t off = (size_t)m * H + jj;
        const float cn = fg * cb[off] + ig * gg;
        cb[off] = cn;
        hout[off] = f2bf(og * tanhf(cn));
    }
}

// ---------------- combine phase ----------------
__device__ void combine_phase(const MP& P, int wg)
{
#pragma unroll
    for (int rep = 0; rep < 2; ++rep) {
        const size_t idx = (size_t)wg * 512 + rep * 256 + threadIdx.x;  // 0..B*H-1
        const float hm = 0.5f * (bf2f(P.h0a[idx]) + bf2f(P.h1a[idx]));
        const float cm = 0.5f * (P.c0[idx] + P.c1[idx]);
        const ushort hb = f2bf(hm);
#pragma unroll
        for (int f = 0; f < Fh; ++f) { P.dh0[f * BH + idx] = hb; P.dc[f * BH + idx] = cm; }
        if (idx < (size_t)Bsz * Fh) {
            const int b = (int)(idx >> 3), f = (int)(idx & 7);
            P.din[idx] = P.x[(size_t)b * XROW + (TIN - 1) * Fh + f];
        }
    }
}

// ---------------- decoder LSTM+fc1+qk+vw phase (16 rows per WG) ----------------
__device__ void dec_phase(const MP& P, int wg, int t,
                          ushort (*h2s)[264], ushort (*as)[264])
{
    const int f = wg & 7, mb = wg >> 3;   // 64 row-blocks x 8 f
    const int m0 = mb * 16;
    const int tid = threadIdx.x;
    const int l = tid & 63, w = tid >> 6;
    const int lr = l & 15, lq = l >> 4, lk = lq * 8;

    const ushort* dhin = (t & 1) ? P.dh1 : P.dh0;
    ushort*       dhout = (t & 1) ? P.dh0 : P.dh1;

    // ---- LSTM gates: 16 rows x 1024 gate-cols; wave w covers j in [w*64, w*64+64) ----
    bf16x8 af[8];
    {
        const ushort* hrow = dhin + ((size_t)f * Bsz + m0 + lr) * H + lk;
#pragma unroll
        for (int ks = 0; ks < 8; ++ks) af[ks] = *(const bf16x8*)(hrow + ks * 32);
    }
    const ushort* Wbase = P.wdWhh + (size_t)f * (H4 * H);
    const float* bi = P.dbih + f * H4;
    const float* bh = P.dbhh + f * H4;
    const float* wx = P.dWih + f * H4;
    float* cb = P.dc + (size_t)f * BH;
    ushort* hog = dhout + (size_t)f * BH;

    for (int jf = 0; jf < 4; ++jf) {
        const int j0 = w * 64 + jf * 16;
        f32x4 acc[4] = {};
#pragma unroll
        for (int g = 0; g < 4; ++g) {
            const ushort* wr = Wbase + (size_t)(g * H + j0 + lr) * H + lk;
#pragma unroll
            for (int ks = 0; ks < 8; ++ks) {
                bf16x8 bf = *(const bf16x8*)(wr + ks * 32);
                acc[g] = __builtin_amdgcn_mfma_f32_16x16x32_bf16(af[ks], bf, acc[g], 0, 0, 0);
            }
        }
        const int j = j0 + lr;
#pragma unroll
        for (int r = 0; r < 4; ++r) {
            const int mloc = lq * 4 + r;
            const int m = m0 + mloc;
            const float xi = P.din[m * Fh + f];
            float pre[4];
#pragma unroll
            for (int g = 0; g < 4; ++g)
                pre[g] = acc[g][r] + bi[g * H + j] + bh[g * H + j] + xi * wx[g * H + j];
            const float ig = sigmf(pre[0]);
            const float fg = sigmf(pre[1]);
            const float gg = tanhf(pre[2]);
            const float og = sigmf(pre[3]);
            const size_t off = (size_t)m * H + j;
            const float cn = fg * cb[off] + ig * gg;
            cb[off] = cn;
            const ushort hb = f2bf(og * tanhf(cn));
            hog[off] = hb;
            h2s[mloc][j] = hb;
        }
    }
    __syncthreads();

    // ---- fc1: a = leaky(h2 @ f1W^T + f1b), 16 x 256; wave w: n in [w*64, +64) ----
    {
        const ushort* Wf = P.wf1W + (size_t)f * H * H;
#pragma unroll
        for (int cf = 0; cf < 4; ++cf) {
            const int n0 = w * 64 + cf * 16;
            f32x4 acc = {};
#pragma unroll
            for (int ks = 0; ks < 8; ++ks) {
                bf16x8 a8 = *(const bf16x8*)&h2s[lr][ks * 32 + lk];
                bf16x8 b8 = *(const bf16x8*)(Wf + (size_t)(n0 + lr) * H + ks * 32 + lk);
                acc = __builtin_amdgcn_mfma_f32_16x16x32_bf16(a8, b8, acc, 0, 0, 0);
            }
            const int n = n0 + lr;
            const float bv = P.f1b[f * H + n];
#pragma unroll
            for (int r = 0; r < 4; ++r) {
                float v = acc[r] + bv;
                v = (v > 0.f) ? v : 0.01f * v;
                as[lq * 4 + r][n] = f2bf(v);
            }
        }
    }
    __syncthreads();

    // ---- qk: 16 x 512; wave w: n in [w*128, +128) ----
    {
        const ushort* Wi = P.winW + (size_t)f * 768 * H;
#pragma unroll
        for (int cf = 0; cf < 8; ++cf) {
            const int n0 = w * 128 + cf * 16;
            f32x4 acc = {};
#pragma unroll
            for (int ks = 0; ks < 8; ++ks) {
                bf16x8 a8 = *(const bf16x8*)&as[lr][ks * 32 + lk];
                bf16x8 b8 = *(const bf16x8*)(Wi + (size_t)(n0 + lr) * H + ks * 32 + lk);
                acc = __builtin_amdgcn_mfma_f32_16x16x32_bf16(a8, b8, acc, 0, 0, 0);
            }
            const int n = n0 + lr;
            const float bv = P.inb[f * 768 + n];
#pragma unroll
            for (int r = 0; r < 4; ++r) {
                const float v = acc[r] + bv;
                const int m = m0 + lq * 4 + r;
                if (n0 < 256)
                    P.qbuf[((size_t)f * Bsz + m) * H + n] = f2bf(v * 0.0625f);
                else
                    P.kbuf[((size_t)f * Bsz + m) * H + (n - 256)] = f2bf(v);
            }
        }
    }

    // ---- vw[m] = a[m].u[f] + d[f] (4 rows per wave) ----
    const float4 u4 = *(const float4*)(P.u + f * H + l * 4);
#pragma unroll
    for (int rr = 0; rr < 4; ++rr) {
        const int mloc = w * 4 + rr;
        const ushort4 a4 = *(const ushort4*)&as[mloc][l * 4];
        float s = bf2f(a4.x) * u4.x + bf2f(a4.y) * u4.y
                + bf2f(a4.z) * u4.z + bf2f(a4.w) * u4.w;
#pragma unroll
        for (int d = 1; d < 64; d <<= 1) s += __shfl_xor(s, d);
        if (l == 0) P.vw[f * Bsz + m0 + mloc] = s + P.dconst[f];
    }
}

// ---------------- attention phase (verbatim, re-gridded) ----------------
__device__ void attn_phase(const MP& P, int wg, int t, float (*tri)[16][4])
{
    const int f = wg & 7, qb = wg >> 3;
    const int q0 = qb * 16;
    const int tid = threadIdx.x;
    const int l = tid & 63, w = tid >> 6;
    const int lr = l & 15, lq = l >> 4, lk = lq * 8;

    bf16x8 qf[8];
    {
        const ushort* qrow = P.qbuf + ((size_t)f * Bsz + q0 + lr) * H + lk;
#pragma unroll
        for (int ks = 0; ks < 8; ++ks) qf[ks] = *(const bf16x8*)(qrow + ks * 32);
    }

    float mM = -1e30f, lS = 0.f, oS = 0.f;
    const int kb0 = w * 256;
    for (int kf = 0; kf < 16; ++kf) {
        const int kb = kb0 + kf * 16;
        const ushort* krow = P.kbuf + ((size_t)f * Bsz + kb + lr) * H + lk;
        f32x4 acc = {};
#pragma unroll
        for (int ks = 0; ks < 8; ++ks) {
            bf16x8 k8 = *(const bf16x8*)(krow + ks * 32);
            acc = __builtin_amdgcn_mfma_f32_16x16x32_bf16(k8, qf[ks], acc, 0, 0, 0);
        }
        const float4 v4 = *(const float4*)(P.vw + f * Bsz + kb + lq * 4);
        const float mx = fmaxf(fmaxf(acc[0], acc[1]), fmaxf(acc[2], acc[3]));
        const float mn = fmaxf(mM, mx);
        const float sc = __expf(mM - mn);
        const float e0 = __expf(acc[0] - mn), e1 = __expf(acc[1] - mn);
        const float e2 = __expf(acc[2] - mn), e3 = __expf(acc[3] - mn);
        lS = lS * sc + (e0 + e1 + e2 + e3);
        oS = oS * sc + (e0 * v4.x + e1 * v4.y + e2 * v4.z + e3 * v4.w);
        mM = mn;
    }
#pragma unroll
    for (int d = 16; d < 64; d <<= 1) {
        const float m2 = __shfl_xor(mM, d), l2 = __shfl_xor(lS, d), o2 = __shfl_xor(oS, d);
        const float mn = fmaxf(mM, m2);
        const float sa = __expf(mM - mn), sb = __expf(m2 - mn);
        lS = lS * sa + l2 * sb;
        oS = oS * sa + o2 * sb;
        mM = mn;
    }
    if (l < 16) { tri[w][l][0] = mM; tri[w][l][1] = lS; tri[w][l][2] = oS; }
    __syncthreads();
    if (tid < 16) {
        float M = tri[0][tid][0], L = tri[0][tid][1], O = tri[0][tid][2];
#pragma unroll
        for (int ww = 1; ww < 4; ++ww) {
            const float m2 = tri[ww][tid][0], l2 = tri[ww][tid][1], o2 = tri[ww][tid][2];
            const float mn = fmaxf(M, m2);
            const float sa = __expf(M - mn), sb = __expf(m2 - mn);
            L = L * sa + l2 * sb;
            O = O * sa + o2 * sb;
            M = mn;
        }
        float val = O / L + P.ccv[f];
        val = (val > 0.f) ? val : 0.01f * val;
        const int b = q0 + tid;
        P.out[(size_t)b * (TOUT * Fh) + (size_t)t * Fh + f] = val;
        P.din[b * Fh + f] = val;
    }
    __syncthreads();
}

// ---------------- the mega-kernel ----------------
__global__ __launch_bounds__(256, 2)
void mega_kernel(MP P)
{
    __shared__ ushort h2s[16][264];
    __shared__ ushort as[16][264];
    __shared__ float tri[4][16][4];
    const int wg = blockIdx.x;
    unsigned ph = 0;

    for (int i = 0; i <= TIN; ++i) {
        enc_phase(P, wg, i);
        gbar(P.bar, ++ph * NWG);
    }
    combine_phase(P, wg);
    gbar(P.bar, ++ph * NWG);
    for (int t = 0; t < TOUT; ++t) {
        dec_phase(P, wg, t, h2s, as);
        gbar(P.bar, ++ph * NWG);
        attn_phase(P, wg, t, tri);
        gbar(P.bar, ++ph * NWG);
    }
}

extern "C" void kernel_launch(void* const* d_in, const int* in_sizes, int n_in,
                              void* d_out, int out_size, void* d_ws, size_t ws_size,
                              hipStream_t stream)
{
    const float* x     = (const float*)d_in[0];
    const float* eWih0 = (const float*)d_in[1];
    const float* eWhh0 = (const float*)d_in[2];
    const float* ebih0 = (const float*)d_in[3];
    const float* ebhh0 = (const float*)d_in[4];
    const float* eWih1 = (const float*)d_in[5];
    const float* eWhh1 = (const float*)d_in[6];
    const float* ebih1 = (const float*)d_in[7];
    const float* ebhh1 = (const float*)d_in[8];
    const float* dWih  = (const float*)d_in[9];
    const float* dWhh  = (const float*)d_in[10];
    const float* dbih  = (const float*)d_in[11];
    const float* dbhh  = (const float*)d_in[12];
    const float* f1W   = (const float*)d_in[13];
    const float* f1b   = (const float*)d_in[14];
    const float* inW   = (const float*)d_in[15];
    const float* inb   = (const float*)d_in[16];
    const float* oW    = (const float*)d_in[17];
    const float* ob    = (const float*)d_in[18];
    const float* f2W   = (const float*)d_in[19];
    const float* f2b   = (const float*)d_in[20];

    // ---- workspace layout ----
    char* base = (char*)d_ws;
    size_t o = 0;
    auto alloc = [&](size_t bytes) { void* p = base + o; o += (bytes + 255) & ~(size_t)255; return p; };
    float*  c0   = (float*)alloc(BH * 4);
    float*  c1   = (float*)alloc(BH * 4);
    ushort* h0a  = (ushort*)alloc(BH * 2);
    ushort* h1a  = (ushort*)alloc(BH * 2);
    ushort* h0b  = (ushort*)alloc(BH * 2);
    ushort* h1b  = (ushort*)alloc(BH * 2);
    ushort* dh0  = (ushort*)alloc(8 * BH * 2);
    ushort* dh1  = (ushort*)alloc(8 * BH * 2);
    float*  dc   = (float*)alloc(8 * BH * 4);
    ushort* qbuf = (ushort*)alloc(8 * BH * 2);
    ushort* kbuf = (ushort*)alloc(8 * BH * 2);
    float*  vwb  = (float*)alloc((size_t)Fh * Bsz * 4);
    float*  din  = (float*)alloc((size_t)Bsz * Fh * 4);
    float*  ubuf = (float*)alloc((size_t)Fh * H * 4);
    float*  dbuf = (float*)alloc(Fh * 4);
    float*  ccb  = (float*)alloc(Fh * 4);
    ushort* wWhh0 = (ushort*)alloc((size_t)H4 * H * 2);
    ushort* wWih1 = (ushort*)alloc((size_t)H4 * H * 2);
    ushort* wWhh1 = (ushort*)alloc((size_t)H4 * H * 2);
    ushort* wdWhh = (ushort*)alloc((size_t)8 * H4 * H * 2);
    ushort* wf1W  = (ushort*)alloc((size_t)8 * H * H * 2);
    ushort* winW  = (ushort*)alloc((size_t)8 * 768 * H * 2);
    unsigned* bar = (unsigned*)alloc(256);

    const dim3 blk(256);

    // zero c0,c1,h0a,h1a (contiguous at ws start) and barrier counter
    hipMemsetAsync(d_ws, 0, BH * 4 * 2 + BH * 2 * 2, stream);
    hipMemsetAsync(bar, 0, 256, stream);

    // ---- weight casts + precompute ----
    cast_f32_bf16<<<dim3(512), blk, 0, stream>>>(eWhh0, wWhh0, H4 * H);
    cast_f32_bf16<<<dim3(512), blk, 0, stream>>>(eWih1, wWih1, H4 * H);
    cast_f32_bf16<<<dim3(512), blk, 0, stream>>>(eWhh1, wWhh1, H4 * H);
    cast_f32_bf16<<<dim3(1024), blk, 0, stream>>>(dWhh, wdWhh, 8 * H4 * H);
    cast_f32_bf16<<<dim3(512), blk, 0, stream>>>(f1W, wf1W, 8 * H * H);
    cast_f32_bf16<<<dim3(1024), blk, 0, stream>>>(inW, winW, 8 * 768 * H);
    precompute_kernel<<<dim3(8), blk, 0, stream>>>(oW, ob, f2W, f2b, inW, inb,
                                                   ubuf, dbuf, ccb);

    // ---- one persistent mega-kernel for encoder + decoder ----
    MP P;
    P.x = x; P.eWih0 = eWih0; P.ebih0 = ebih0; P.ebhh0 = ebhh0;
    P.ebih1 = ebih1; P.ebhh1 = ebhh1;
    P.wWhh0 = wWhh0; P.wWih1 = wWih1; P.wWhh1 = wWhh1;
    P.dWih = dWih; P.dbih = dbih; P.dbhh = dbhh; P.f1b = f1b; P.inb = inb;
    P.wdWhh = wdWhh; P.wf1W = wf1W; P.winW = winW;
    P.u = ubuf; P.dconst = dbuf; P.ccv = ccb;
    P.c0 = c0; P.c1 = c1; P.dc = dc; P.vw = vwb; P.din = din;
    P.out = (float*)d_out;
    P.h0a = h0a; P.h1a = h1a; P.h0b = h0b; P.h1b = h1b;
    P.dh0 = dh0; P.dh1 = dh1; P.qbuf = qbuf; P.kbuf = kbuf;
    P.bar = bar;

    mega_kernel<<<dim3(NWG), blk, 0, stream>>>(P);

    (void)in_sizes; (void)n_in; (void)out_size; (void)ws_size;
}

// Round 5
// 12317.078 us; speedup vs baseline: 1.7775x; 1.7775x over previous
//
#include <hip/hip_runtime.h>
#include <math.h>

#define H 256
#define H4 1024
#define Bsz 1024
#define TIN 168
#define TOUT 24
#define Fh 8
#define XROW (TIN*Fh)
#define BH ((size_t)Bsz * H)   // 262144

typedef __attribute__((ext_vector_type(8))) short bf16x8;
typedef __attribute__((ext_vector_type(4))) float f32x4;

__device__ __forceinline__ ushort f2bf(float f) {
    union { float f; unsigned u; } v; v.f = f;
    unsigned r = v.u + 0x7fff + ((v.u >> 16) & 1);
    return (ushort)(r >> 16);
}
__device__ __forceinline__ float bf2f(ushort u) {
    union { unsigned u; float f; } v; v.u = ((unsigned)u) << 16;
    return v.f;
}
__device__ __forceinline__ float sigmf(float x) {
    return __fdividef(1.0f, 1.0f + __expf(-x));
}
__device__ __forceinline__ float tanhf_(float x) {
    const float e = __expf(-2.0f * fabsf(x));
    const float t = __fdividef(1.0f - e, 1.0f + e);
    return copysignf(t, x);
}

__global__ __launch_bounds__(256)
void cast_f32_bf16(const float* __restrict__ in, ushort* __restrict__ out, int n) {
    int i = blockIdx.x * 256 + threadIdx.x;
    const int stride = gridDim.x * 256;
    for (; i < n; i += stride) out[i] = f2bf(in[i]);
}

// Wih0 (1024 x 8) -> bf16 padded to (1024 x 32), cols 8..31 zero.
__global__ __launch_bounds__(256)
void cast_pad_wih0(const float* __restrict__ in, ushort* __restrict__ out) {
    const int idx = blockIdx.x * 256 + threadIdx.x;   // 0 .. 1024*32
    const int row = idx >> 5, c = idx & 31;
    out[idx] = (c < 8) ? f2bf(in[row * 8 + c]) : (ushort)0;
}

// Precompute (once): w[f]=f2W@oW; u[f]=inW_v^T@w; d[f]=inb_v.w; cc[f]=ob.f2W+f2b
__global__ __launch_bounds__(256)
void precompute_kernel(const float* __restrict__ oW, const float* __restrict__ ob,
                       const float* __restrict__ f2W, const float* __restrict__ f2b,
                       const float* __restrict__ inW, const float* __restrict__ inb,
                       float* __restrict__ u, float* __restrict__ dconst,
                       float* __restrict__ ccv)
{
    __shared__ float wsh[256];
    const int f = blockIdx.x;
    const int tid = threadIdx.x;
    float s = 0.f;
    for (int i = 0; i < 256; ++i)
        s += f2W[f * 256 + i] * oW[(size_t)f * 65536 + (size_t)i * 256 + tid];
    wsh[tid] = s;
    __syncthreads();
    float su = 0.f;
    for (int n = 0; n < 256; ++n)
        su += wsh[n] * inW[(size_t)f * 768 * 256 + (size_t)(512 + n) * 256 + tid];
    u[f * 256 + tid] = su;
    if (tid == 0) {
        float dd = 0.f, cc = 0.f;
        for (int n = 0; n < 256; ++n) dd += wsh[n] * inb[f * 768 + 512 + n];
        for (int i = 0; i < 256; ++i) cc += ob[f * 256 + i] * f2W[f * 256 + i];
        dconst[f] = dd;
        ccv[f] = cc + f2b[f];
    }
}

// ---------------------------------------------------------------------------
// Persistent batch-parallel encoder: 32 WGs x 32 batch rows, all 168 steps,
// both layers, NO grid sync (recurrence is row-local). h in LDS, c in regs.
// Wave w owns hidden units j in [64w, 64w+64). Weights stream from L2.
// ---------------------------------------------------------------------------
__global__ __launch_bounds__(256, 1)
void enc_persist(const float* __restrict__ x,
                 const ushort* __restrict__ Whh0, const ushort* __restrict__ Wih0p,
                 const ushort* __restrict__ Wih1, const ushort* __restrict__ Whh1,
                 const float* __restrict__ bih0, const float* __restrict__ bhh0,
                 const float* __restrict__ bih1, const float* __restrict__ bhh1,
                 ushort* __restrict__ dh, float* __restrict__ dcb,
                 float* __restrict__ din)
{
    __shared__ ushort h0L[32][264];
    __shared__ ushort h1L[32][264];
    __shared__ ushort xL[32][32];
    const int tid = threadIdx.x;
    const int l = tid & 63, w = tid >> 6;
    const int lr = l & 15, lq = l >> 4, lk = lq * 8;
    const int m0 = blockIdx.x * 32;

    for (int e = tid; e < 32 * 264; e += 256) { (&h0L[0][0])[e] = 0; (&h1L[0][0])[e] = 0; }
    for (int e = tid; e < 32 * 32; e += 256) (&xL[0][0])[e] = 0;

    float b0s[4][4], b1s[4][4];
#pragma unroll
    for (int jt = 0; jt < 4; ++jt)
#pragma unroll
        for (int g = 0; g < 4; ++g) {
            const int j = w * 64 + jt * 16 + lr;
            b0s[jt][g] = bih0[g * H + j] + bhh0[g * H + j];
            b1s[jt][g] = bih1[g * H + j] + bhh1[g * H + j];
        }
    f32x4 c0r[2][4] = {};
    f32x4 c1r[2][4] = {};

    __syncthreads();

    for (int t = 0; t < TIN; ++t) {
        {   // stage x(t) for our 32 rows into bf16 LDS (cols 8..31 stay 0)
            const int r = tid >> 3, ki = tid & 7;
            xL[r][ki] = f2bf(x[(size_t)(m0 + r) * XROW + t * Fh + ki]);
        }
        __syncthreads();                       // xL ready; prev h1L writes done
        bf16x8 a0[2][8], ax[2];
#pragma unroll
        for (int m = 0; m < 2; ++m) {
#pragma unroll
            for (int k = 0; k < 8; ++k)
                a0[m][k] = *(const bf16x8*)&h0L[m * 16 + lr][k * 32 + lk];
            ax[m] = *(const bf16x8*)&xL[m * 16 + lr][lk];
        }
        __syncthreads();                       // frag reads done -> h0L writable
        // ---- layer 0 ----
#pragma unroll 1
        for (int jt = 0; jt < 4; ++jt) {
            const int jb = w * 64 + jt * 16;
            f32x4 acc[2][4] = {};
#pragma unroll
            for (int k = 0; k < 8; ++k)
#pragma unroll
                for (int g = 0; g < 4; ++g) {
                    const bf16x8 bf = *(const bf16x8*)(Whh0 + (size_t)(g * H + jb + lr) * H + k * 32 + lk);
                    acc[0][g] = __builtin_amdgcn_mfma_f32_16x16x32_bf16(a0[0][k], bf, acc[0][g], 0, 0, 0);
                    acc[1][g] = __builtin_amdgcn_mfma_f32_16x16x32_bf16(a0[1][k], bf, acc[1][g], 0, 0, 0);
                }
#pragma unroll
            for (int g = 0; g < 4; ++g) {
                const bf16x8 bx = *(const bf16x8*)(Wih0p + (size_t)(g * H + jb + lr) * 32 + lk);
                acc[0][g] = __builtin_amdgcn_mfma_f32_16x16x32_bf16(ax[0], bx, acc[0][g], 0, 0, 0);
                acc[1][g] = __builtin_amdgcn_mfma_f32_16x16x32_bf16(ax[1], bx, acc[1][g], 0, 0, 0);
            }
#pragma unroll
            for (int m = 0; m < 2; ++m)
#pragma unroll
                for (int r = 0; r < 4; ++r) {
                    const float ig = sigmf(acc[m][0][r] + b0s[jt][0]);
                    const float fg = sigmf(acc[m][1][r] + b0s[jt][1]);
                    const float gg = tanhf_(acc[m][2][r] + b0s[jt][2]);
                    const float og = sigmf(acc[m][3][r] + b0s[jt][3]);
                    const float cn = fg * c0r[m][jt][r] + ig * gg;
                    c0r[m][jt][r] = cn;
                    h0L[m * 16 + lq * 4 + r][jb + lr] = f2bf(og * tanhf_(cn));
                }
        }
        __syncthreads();                       // h0L(new) complete
        bf16x8 an[2][8], a1[2][8];
#pragma unroll
        for (int m = 0; m < 2; ++m)
#pragma unroll
            for (int k = 0; k < 8; ++k) {
                an[m][k] = *(const bf16x8*)&h0L[m * 16 + lr][k * 32 + lk];
                a1[m][k] = *(const bf16x8*)&h1L[m * 16 + lr][k * 32 + lk];
            }
        __syncthreads();                       // frag reads done -> h1L writable
        // ---- layer 1: gates = h0_new@Wih1^T + h1@Whh1^T ----
#pragma unroll 1
        for (int jt = 0; jt < 4; ++jt) {
            const int jb = w * 64 + jt * 16;
            f32x4 acc[2][4] = {};
#pragma unroll
            for (int k = 0; k < 8; ++k)
#pragma unroll
                for (int g = 0; g < 4; ++g) {
                    const bf16x8 b1 = *(const bf16x8*)(Wih1 + (size_t)(g * H + jb + lr) * H + k * 32 + lk);
                    acc[0][g] = __builtin_amdgcn_mfma_f32_16x16x32_bf16(an[0][k], b1, acc[0][g], 0, 0, 0);
                    acc[1][g] = __builtin_amdgcn_mfma_f32_16x16x32_bf16(an[1][k], b1, acc[1][g], 0, 0, 0);
                    const bf16x8 b2 = *(const bf16x8*)(Whh1 + (size_t)(g * H + jb + lr) * H + k * 32 + lk);
                    acc[0][g] = __builtin_amdgcn_mfma_f32_16x16x32_bf16(a1[0][k], b2, acc[0][g], 0, 0, 0);
                    acc[1][g] = __builtin_amdgcn_mfma_f32_16x16x32_bf16(a1[1][k], b2, acc[1][g], 0, 0, 0);
                }
#pragma unroll
            for (int m = 0; m < 2; ++m)
#pragma unroll
                for (int r = 0; r < 4; ++r) {
                    const float ig = sigmf(acc[m][0][r] + b1s[jt][0]);
                    const float fg = sigmf(acc[m][1][r] + b1s[jt][1]);
                    const float gg = tanhf_(acc[m][2][r] + b1s[jt][2]);
                    const float og = sigmf(acc[m][3][r] + b1s[jt][3]);
                    const float cn = fg * c1r[m][jt][r] + ig * gg;
                    c1r[m][jt][r] = cn;
                    h1L[m * 16 + lq * 4 + r][jb + lr] = f2bf(og * tanhf_(cn));
                }
        }
        // loop-top sync orders h1L writes vs next reads
    }
    __syncthreads();
    // ---- tail: combine + broadcast to decoder state, din init ----
    for (int e = tid; e < 32 * H; e += 256) {
        const int r = e >> 8, cc = e & 255;
        const ushort hb = f2bf(0.5f * (bf2f(h0L[r][cc]) + bf2f(h1L[r][cc])));
        const size_t idx = (size_t)(m0 + r) * H + cc;
#pragma unroll
        for (int f = 0; f < Fh; ++f) dh[f * BH + idx] = hb;
    }
#pragma unroll
    for (int m = 0; m < 2; ++m)
#pragma unroll
        for (int jt = 0; jt < 4; ++jt)
#pragma unroll
            for (int r = 0; r < 4; ++r) {
                const float cm = 0.5f * (c0r[m][jt][r] + c1r[m][jt][r]);
                const size_t idx = (size_t)(m0 + m * 16 + lq * 4 + r) * H
                                 + (w * 64 + jt * 16 + lr);
#pragma unroll
                for (int f = 0; f < Fh; ++f) dcb[f * BH + idx] = cm;
            }
    {
        const int r = tid >> 3, f = tid & 7;
        din[(m0 + r) * Fh + f] = x[(size_t)(m0 + r) * XROW + (TIN - 1) * Fh + f];
    }
}

// ---------------------------------------------------------------------------
// Fused decoder step: [attn(t-1) -> out + din(LDS)] then [dec(t): LSTM + fc1 +
// qk + vw]. 256 WGs = f(=bid&7, XCD-local weights) x 32 rows. Cross-WG data
// (k, vw) parity-double-buffered across launches; din stays in LDS.
// ---------------------------------------------------------------------------
template<int DO_ATTN, int DO_DEC>
__global__ __launch_bounds__(256, 1)
void dec_step(const ushort* __restrict__ qprev, const ushort* __restrict__ kprev,
              const float* __restrict__ vwprev,
              ushort* __restrict__ qcur, ushort* __restrict__ kcur,
              float* __restrict__ vwcur,
              ushort* __restrict__ dhg, float* __restrict__ dcg,
              const ushort* __restrict__ Whh, const float* __restrict__ Wih,
              const float* __restrict__ bih, const float* __restrict__ bhh,
              const ushort* __restrict__ f1Wb, const float* __restrict__ f1b,
              const ushort* __restrict__ inWb, const float* __restrict__ inb,
              const float* __restrict__ u, const float* __restrict__ dconst,
              const float* __restrict__ ccv, const float* __restrict__ din0,
              float* __restrict__ out, int t)
{
    __shared__ ushort h2s[32][264];
    __shared__ ushort as[32][264];
    __shared__ float dinL[32];
    __shared__ float tri[4][2][16][3];
    const int bid = blockIdx.x;
    const int f = bid & 7, mb = bid >> 3;
    const int m0 = mb * 32;
    const int tid = threadIdx.x;
    const int l = tid & 63, w = tid >> 6;
    const int lr = l & 15, lq = l >> 4, lk = lq * 8;

    if (DO_ATTN) {
        bf16x8 qf[2][8];
#pragma unroll
        for (int m = 0; m < 2; ++m)
#pragma unroll
            for (int k = 0; k < 8; ++k)
                qf[m][k] = *(const bf16x8*)(qprev + ((size_t)f * Bsz + m0 + m * 16 + lr) * H + k * 32 + lk);
        float mM0 = -1e30f, lS0 = 0.f, oS0 = 0.f;
        float mM1 = -1e30f, lS1 = 0.f, oS1 = 0.f;
        const int kb0 = w * 256;
        for (int kf = 0; kf < 16; ++kf) {
            const int kb = kb0 + kf * 16;
            f32x4 acc0 = {}, acc1 = {};
#pragma unroll
            for (int k = 0; k < 8; ++k) {
                const bf16x8 k8 = *(const bf16x8*)(kprev + ((size_t)f * Bsz + kb + lr) * H + k * 32 + lk);
                acc0 = __builtin_amdgcn_mfma_f32_16x16x32_bf16(k8, qf[0][k], acc0, 0, 0, 0);
                acc1 = __builtin_amdgcn_mfma_f32_16x16x32_bf16(k8, qf[1][k], acc1, 0, 0, 0);
            }
            const float4 v4 = *(const float4*)(vwprev + f * Bsz + kb + lq * 4);
            {
                const float mx = fmaxf(fmaxf(acc0[0], acc0[1]), fmaxf(acc0[2], acc0[3]));
                const float mn = fmaxf(mM0, mx);
                const float sc = __expf(mM0 - mn);
                const float e0 = __expf(acc0[0] - mn), e1 = __expf(acc0[1] - mn);
                const float e2 = __expf(acc0[2] - mn), e3 = __expf(acc0[3] - mn);
                lS0 = lS0 * sc + (e0 + e1 + e2 + e3);
                oS0 = oS0 * sc + (e0 * v4.x + e1 * v4.y + e2 * v4.z + e3 * v4.w);
                mM0 = mn;
            }
            {
                const float mx = fmaxf(fmaxf(acc1[0], acc1[1]), fmaxf(acc1[2], acc1[3]));
                const float mn = fmaxf(mM1, mx);
                const float sc = __expf(mM1 - mn);
                const float e0 = __expf(acc1[0] - mn), e1 = __expf(acc1[1] - mn);
                const float e2 = __expf(acc1[2] - mn), e3 = __expf(acc1[3] - mn);
                lS1 = lS1 * sc + (e0 + e1 + e2 + e3);
                oS1 = oS1 * sc + (e0 * v4.x + e1 * v4.y + e2 * v4.z + e3 * v4.w);
                mM1 = mn;
            }
        }
#pragma unroll
        for (int d = 16; d < 64; d <<= 1) {
            {
                const float m2 = __shfl_xor(mM0, d), l2 = __shfl_xor(lS0, d), o2 = __shfl_xor(oS0, d);
                const float mn = fmaxf(mM0, m2);
                const float sa = __expf(mM0 - mn), sb = __expf(m2 - mn);
                lS0 = lS0 * sa + l2 * sb; oS0 = oS0 * sa + o2 * sb; mM0 = mn;
            }
            {
                const float m2 = __shfl_xor(mM1, d), l2 = __shfl_xor(lS1, d), o2 = __shfl_xor(oS1, d);
                const float mn = fmaxf(mM1, m2);
                const float sa = __expf(mM1 - mn), sb = __expf(m2 - mn);
                lS1 = lS1 * sa + l2 * sb; oS1 = oS1 * sa + o2 * sb; mM1 = mn;
            }
        }
        if (l < 16) {
            tri[w][0][l][0] = mM0; tri[w][0][l][1] = lS0; tri[w][0][l][2] = oS0;
            tri[w][1][l][0] = mM1; tri[w][1][l][1] = lS1; tri[w][1][l][2] = oS1;
        }
        __syncthreads();
        if (tid < 32) {
            const int m = tid >> 4, qr = tid & 15;
            float M = tri[0][m][qr][0], L = tri[0][m][qr][1], O = tri[0][m][qr][2];
#pragma unroll
            for (int ww = 1; ww < 4; ++ww) {
                const float m2 = tri[ww][m][qr][0], l2 = tri[ww][m][qr][1], o2 = tri[ww][m][qr][2];
                const float mn = fmaxf(M, m2);
                const float sa = __expf(M - mn), sb = __expf(m2 - mn);
                L = L * sa + l2 * sb; O = O * sa + o2 * sb; M = mn;
            }
            float val = __fdividef(O, L) + ccv[f];
            val = (val > 0.f) ? val : 0.01f * val;
            const int b = m0 + m * 16 + qr;
            out[(size_t)b * (TOUT * Fh) + (size_t)(t - 1) * Fh + f] = val;
            dinL[m * 16 + qr] = val;
        }
        __syncthreads();
    }

    if (DO_DEC) {
        float bsum[4][4], wxr[4][4];
#pragma unroll
        for (int jt = 0; jt < 4; ++jt)
#pragma unroll
            for (int g = 0; g < 4; ++g) {
                const int j = w * 64 + jt * 16 + lr;
                bsum[jt][g] = bih[f * H4 + g * H + j] + bhh[f * H4 + g * H + j];
                wxr[jt][g] = Wih[f * H4 + g * H + j];
            }
        bf16x8 af[2][8];
#pragma unroll
        for (int m = 0; m < 2; ++m)
#pragma unroll
            for (int k = 0; k < 8; ++k)
                af[m][k] = *(const bf16x8*)(dhg + ((size_t)f * Bsz + m0 + m * 16 + lr) * H + k * 32 + lk);
        __syncthreads();   // all waves' dhg reads complete before in-place writes
        const ushort* Wb = Whh + (size_t)f * (H4 * H);
#pragma unroll 1
        for (int jt = 0; jt < 4; ++jt) {
            const int jb = w * 64 + jt * 16;
            f32x4 acc[2][4] = {};
#pragma unroll
            for (int k = 0; k < 8; ++k)
#pragma unroll
                for (int g = 0; g < 4; ++g) {
                    const bf16x8 bf = *(const bf16x8*)(Wb + (size_t)(g * H + jb + lr) * H + k * 32 + lk);
                    acc[0][g] = __builtin_amdgcn_mfma_f32_16x16x32_bf16(af[0][k], bf, acc[0][g], 0, 0, 0);
                    acc[1][g] = __builtin_amdgcn_mfma_f32_16x16x32_bf16(af[1][k], bf, acc[1][g], 0, 0, 0);
                }
#pragma unroll
            for (int m = 0; m < 2; ++m)
#pragma unroll
                for (int r = 0; r < 4; ++r) {
                    const int row = m * 16 + lq * 4 + r;
                    const float xi = DO_ATTN ? dinL[row] : din0[(m0 + row) * Fh + f];
                    const float ig = sigmf(acc[m][0][r] + bsum[jt][0] + xi * wxr[jt][0]);
                    const float fg = sigmf(acc[m][1][r] + bsum[jt][1] + xi * wxr[jt][1]);
                    const float gg = tanhf_(acc[m][2][r] + bsum[jt][2] + xi * wxr[jt][2]);
                    const float og = sigmf(acc[m][3][r] + bsum[jt][3] + xi * wxr[jt][3]);
                    const size_t off = ((size_t)f * Bsz + m0 + row) * H + jb + lr;
                    const float cn = fg * dcg[off] + ig * gg;
                    dcg[off] = cn;
                    const ushort hb = f2bf(og * tanhf_(cn));
                    dhg[off] = hb;
                    h2s[row][jb + lr] = hb;
                }
        }
        __syncthreads();
        // ---- fc1 ----
        bf16x8 a2[2][8];
#pragma unroll
        for (int m = 0; m < 2; ++m)
#pragma unroll
            for (int k = 0; k < 8; ++k)
                a2[m][k] = *(const bf16x8*)&h2s[m * 16 + lr][k * 32 + lk];
        const ushort* Wf = f1Wb + (size_t)f * H * H;
#pragma unroll 1
        for (int nt = 0; nt < 4; ++nt) {
            const int n0 = w * 64 + nt * 16;
            f32x4 acc0 = {}, acc1 = {};
#pragma unroll
            for (int k = 0; k < 8; ++k) {
                const bf16x8 b8 = *(const bf16x8*)(Wf + (size_t)(n0 + lr) * H + k * 32 + lk);
                acc0 = __builtin_amdgcn_mfma_f32_16x16x32_bf16(a2[0][k], b8, acc0, 0, 0, 0);
                acc1 = __builtin_amdgcn_mfma_f32_16x16x32_bf16(a2[1][k], b8, acc1, 0, 0, 0);
            }
            const float bv = f1b[f * H + n0 + lr];
#pragma unroll
            for (int r = 0; r < 4; ++r) {
                float v0 = acc0[r] + bv; v0 = (v0 > 0.f) ? v0 : 0.01f * v0;
                as[lq * 4 + r][n0 + lr] = f2bf(v0);
                float v1 = acc1[r] + bv; v1 = (v1 > 0.f) ? v1 : 0.01f * v1;
                as[16 + lq * 4 + r][n0 + lr] = f2bf(v1);
            }
        }
        __syncthreads();
        // ---- q,k projection ----
        bf16x8 a3[2][8];
#pragma unroll
        for (int m = 0; m < 2; ++m)
#pragma unroll
            for (int k = 0; k < 8; ++k)
                a3[m][k] = *(const bf16x8*)&as[m * 16 + lr][k * 32 + lk];
        const ushort* Wi = inWb + (size_t)f * 768 * H;
#pragma unroll 1
        for (int nt = 0; nt < 8; ++nt) {
            const int n0 = w * 128 + nt * 16;
            f32x4 acc0 = {}, acc1 = {};
#pragma unroll
            for (int k = 0; k < 8; ++k) {
                const bf16x8 b8 = *(const bf16x8*)(Wi + (size_t)(n0 + lr) * H + k * 32 + lk);
                acc0 = __builtin_amdgcn_mfma_f32_16x16x32_bf16(a3[0][k], b8, acc0, 0, 0, 0);
                acc1 = __builtin_amdgcn_mfma_f32_16x16x32_bf16(a3[1][k], b8, acc1, 0, 0, 0);
            }
            const float bv = inb[f * 768 + n0 + lr];
#pragma unroll
            for (int m = 0; m < 2; ++m)
#pragma unroll
                for (int r = 0; r < 4; ++r) {
                    const float v = (m ? acc1[r] : acc0[r]) + bv;
                    const int mrow = m0 + m * 16 + lq * 4 + r;
                    if (n0 < 256)
                        qcur[((size_t)f * Bsz + mrow) * H + n0 + lr] = f2bf(v * 0.0625f);
                    else
                        kcur[((size_t)f * Bsz + mrow) * H + n0 - 256 + lr] = f2bf(v);
                }
        }
        // ---- vw[m] = a[m].u[f] + d[f] ----
        const float4 u4 = *(const float4*)(u + f * H + l * 4);
#pragma unroll 1
        for (int rr = 0; rr < 8; ++rr) {
            const int mloc = w * 8 + rr;
            const ushort4 a4 = *(const ushort4*)&as[mloc][l * 4];
            float s = bf2f(a4.x) * u4.x + bf2f(a4.y) * u4.y
                    + bf2f(a4.z) * u4.z + bf2f(a4.w) * u4.w;
#pragma unroll
            for (int d = 1; d < 64; d <<= 1) s += __shfl_xor(s, d);
            if (l == 0) vwcur[f * Bsz + m0 + mloc] = s + dconst[f];
        }
    }
}

extern "C" void kernel_launch(void* const* d_in, const int* in_sizes, int n_in,
                              void* d_out, int out_size, void* d_ws, size_t ws_size,
                              hipStream_t stream)
{
    const float* x     = (const float*)d_in[0];
    const float* eWih0 = (const float*)d_in[1];
    const float* eWhh0 = (const float*)d_in[2];
    const float* ebih0 = (const float*)d_in[3];
    const float* ebhh0 = (const float*)d_in[4];
    const float* eWih1 = (const float*)d_in[5];
    const float* eWhh1 = (const float*)d_in[6];
    const float* ebih1 = (const float*)d_in[7];
    const float* ebhh1 = (const float*)d_in[8];
    const float* dWih  = (const float*)d_in[9];
    const float* dWhh  = (const float*)d_in[10];
    const float* dbih  = (const float*)d_in[11];
    const float* dbhh  = (const float*)d_in[12];
    const float* f1W   = (const float*)d_in[13];
    const float* f1b   = (const float*)d_in[14];
    const float* inW   = (const float*)d_in[15];
    const float* inb   = (const float*)d_in[16];
    const float* oW    = (const float*)d_in[17];
    const float* ob    = (const float*)d_in[18];
    const float* f2W   = (const float*)d_in[19];
    const float* f2b   = (const float*)d_in[20];
    float* out = (float*)d_out;

    // ---- workspace ----
    char* base = (char*)d_ws;
    size_t o = 0;
    auto alloc = [&](size_t bytes) { void* p = base + o; o += (bytes + 255) & ~(size_t)255; return p; };
    ushort* qb[2]; ushort* kb[2]; float* vw[2];
    qb[0] = (ushort*)alloc(8 * BH * 2);
    qb[1] = (ushort*)alloc(8 * BH * 2);
    kb[0] = (ushort*)alloc(8 * BH * 2);
    kb[1] = (ushort*)alloc(8 * BH * 2);
    vw[0] = (float*)alloc((size_t)Fh * Bsz * 4);
    vw[1] = (float*)alloc((size_t)Fh * Bsz * 4);
    ushort* dhg  = (ushort*)alloc(8 * BH * 2);
    float*  dcg  = (float*)alloc(8 * BH * 4);
    float*  din0 = (float*)alloc((size_t)Bsz * Fh * 4);
    float*  ubuf = (float*)alloc((size_t)Fh * H * 4);
    float*  dbuf = (float*)alloc(Fh * 4);
    float*  ccb  = (float*)alloc(Fh * 4);
    ushort* wWhh0 = (ushort*)alloc((size_t)H4 * H * 2);
    ushort* wWih0p= (ushort*)alloc((size_t)H4 * 32 * 2);
    ushort* wWih1 = (ushort*)alloc((size_t)H4 * H * 2);
    ushort* wWhh1 = (ushort*)alloc((size_t)H4 * H * 2);
    ushort* wdWhh = (ushort*)alloc((size_t)8 * H4 * H * 2);
    ushort* wf1W  = (ushort*)alloc((size_t)8 * H * H * 2);
    ushort* winW  = (ushort*)alloc((size_t)8 * 768 * H * 2);

    const dim3 blk(256);

    // ---- weight casts + precompute ----
    cast_f32_bf16<<<dim3(512), blk, 0, stream>>>(eWhh0, wWhh0, H4 * H);
    cast_f32_bf16<<<dim3(512), blk, 0, stream>>>(eWih1, wWih1, H4 * H);
    cast_f32_bf16<<<dim3(512), blk, 0, stream>>>(eWhh1, wWhh1, H4 * H);
    cast_pad_wih0<<<dim3(128), blk, 0, stream>>>(eWih0, wWih0p);
    cast_f32_bf16<<<dim3(1024), blk, 0, stream>>>(dWhh, wdWhh, 8 * H4 * H);
    cast_f32_bf16<<<dim3(512), blk, 0, stream>>>(f1W, wf1W, 8 * H * H);
    cast_f32_bf16<<<dim3(1024), blk, 0, stream>>>(inW, winW, 8 * 768 * H);
    precompute_kernel<<<dim3(8), blk, 0, stream>>>(oW, ob, f2W, f2b, inW, inb,
                                                   ubuf, dbuf, ccb);

    // ---- encoder: ONE persistent launch, no grid sync ----
    enc_persist<<<dim3(32), blk, 0, stream>>>(
        x, wWhh0, wWih0p, wWih1, wWhh1, ebih0, ebhh0, ebih1, ebhh1,
        dhg, dcg, din0);

    // ---- decoder: 25 launches ----
    dec_step<0, 1><<<dim3(256), blk, 0, stream>>>(
        qb[1], kb[1], vw[1], qb[0], kb[0], vw[0], dhg, dcg,
        wdWhh, dWih, dbih, dbhh, wf1W, f1b, winW, inb,
        ubuf, dbuf, ccb, din0, out, 0);
    for (int t = 1; t < TOUT; ++t) {
        const int pp = (t - 1) & 1, pc = t & 1;
        dec_step<1, 1><<<dim3(256), blk, 0, stream>>>(
            qb[pp], kb[pp], vw[pp], qb[pc], kb[pc], vw[pc], dhg, dcg,
            wdWhh, dWih, dbih, dbhh, wf1W, f1b, winW, inb,
            ubuf, dbuf, ccb, din0, out, t);
    }
    dec_step<1, 0><<<dim3(256), blk, 0, stream>>>(
        qb[1], kb[1], vw[1], qb[0], kb[0], vw[0], dhg, dcg,
        wdWhh, dWih, dbih, dbhh, wf1W, f1b, winW, inb,
        ubuf, dbuf, ccb, din0, out, TOUT);

    (void)in_sizes; (void)n_in; (void)out_size; (void)ws_size;
}

// Round 6
// 3680.807 us; speedup vs baseline: 5.9479x; 3.3463x over previous
//
#include <hip/hip_runtime.h>
#include <math.h>

#define H 256
#define H4 1024
#define Bsz 1024
#define TIN 168
#define TOUT 24
#define Fh 8
#define XROW (TIN*Fh)
#define BH ((size_t)Bsz * H)   // 262144

typedef __attribute__((ext_vector_type(8))) short bf16x8;
typedef __attribute__((ext_vector_type(4))) float f32x4;

__device__ __forceinline__ ushort f2bf(float f) {
    union { float f; unsigned u; } v; v.f = f;
    unsigned r = v.u + 0x7fff + ((v.u >> 16) & 1);
    return (ushort)(r >> 16);
}
__device__ __forceinline__ float bf2f(ushort u) {
    union { unsigned u; float f; } v; v.u = ((unsigned)u) << 16;
    return v.f;
}
__device__ __forceinline__ float sigmf(float x) {
    return __fdividef(1.0f, 1.0f + __expf(-x));
}
__device__ __forceinline__ float tanhf_(float x) {
    const float e = __expf(-2.0f * fabsf(x));
    const float t = __fdividef(1.0f - e, 1.0f + e);
    return copysignf(t, x);
}

// ---- MALL-coherent (device-scope) memory helpers: bypass L1/L2 via sc0 sc1 ----
__device__ __forceinline__ void load_coh4(const ushort* p0, const ushort* p1,
                                          const ushort* p2, const ushort* p3,
                                          f32x4& a, f32x4& b, f32x4& c, f32x4& d)
{
    asm volatile(
        "global_load_dwordx4 %0, %4, off sc0 sc1\n\t"
        "global_load_dwordx4 %1, %5, off sc0 sc1\n\t"
        "global_load_dwordx4 %2, %6, off sc0 sc1\n\t"
        "global_load_dwordx4 %3, %7, off sc0 sc1\n\t"
        "s_waitcnt vmcnt(0)"
        : "=&v"(a), "=&v"(b), "=&v"(c), "=&v"(d)
        : "v"(p0), "v"(p1), "v"(p2), "v"(p3)
        : "memory");
}
__device__ __forceinline__ void load_coh8(const ushort* p0, const ushort* p1,
                                          const ushort* p2, const ushort* p3,
                                          const ushort* p4, const ushort* p5,
                                          const ushort* p6, const ushort* p7,
                                          f32x4& a, f32x4& b, f32x4& c, f32x4& d,
                                          f32x4& e, f32x4& f, f32x4& g, f32x4& h)
{
    asm volatile(
        "global_load_dwordx4 %0, %8, off sc0 sc1\n\t"
        "global_load_dwordx4 %1, %9, off sc0 sc1\n\t"
        "global_load_dwordx4 %2, %10, off sc0 sc1\n\t"
        "global_load_dwordx4 %3, %11, off sc0 sc1\n\t"
        "global_load_dwordx4 %4, %12, off sc0 sc1\n\t"
        "global_load_dwordx4 %5, %13, off sc0 sc1\n\t"
        "global_load_dwordx4 %6, %14, off sc0 sc1\n\t"
        "global_load_dwordx4 %7, %15, off sc0 sc1\n\t"
        "s_waitcnt vmcnt(0)"
        : "=&v"(a), "=&v"(b), "=&v"(c), "=&v"(d),
          "=&v"(e), "=&v"(f), "=&v"(g), "=&v"(h)
        : "v"(p0), "v"(p1), "v"(p2), "v"(p3), "v"(p4), "v"(p5), "v"(p6), "v"(p7)
        : "memory");
}
__device__ __forceinline__ void store_coh8B(ushort* p, uint2 v) {
    asm volatile("global_store_dwordx2 %0, %1, off sc0 sc1"
                 :: "v"(p), "v"(v) : "memory");
}

// group barrier: relaxed atomics only (no acquire fence -> L2 never invalidated).
// Data crossing WGs travels via sc0sc1 (MALL) so no cache maintenance is needed.
__device__ __forceinline__ void gbar2(unsigned* cnt, unsigned target) {
    asm volatile("s_waitcnt vmcnt(0)" ::: "memory");  // own sc-stores at MALL
    __syncthreads();
    if (threadIdx.x == 0) {
        __hip_atomic_fetch_add(cnt, 1u, __ATOMIC_RELAXED, __HIP_MEMORY_SCOPE_AGENT);
        int spins = 0;
        while (__hip_atomic_fetch_add(cnt, 0u, __ATOMIC_RELAXED,
                                      __HIP_MEMORY_SCOPE_AGENT) < target) {
            __builtin_amdgcn_s_sleep(1);
            if (++spins > 20000) break;   // failsafe: no hangs, fails absmax instead
        }
    }
    __syncthreads();
    asm volatile("" ::: "memory");
}

__global__ __launch_bounds__(256)
void cast_f32_bf16(const float* __restrict__ in, ushort* __restrict__ out, int n) {
    int i = blockIdx.x * 256 + threadIdx.x;
    const int stride = gridDim.x * 256;
    for (; i < n; i += stride) out[i] = f2bf(in[i]);
}

// Wih0 (1024 x 8) -> bf16 padded to (1024 x 32), cols 8..31 zero.
__global__ __launch_bounds__(256)
void cast_pad_wih0(const float* __restrict__ in, ushort* __restrict__ out) {
    const int idx = blockIdx.x * 256 + threadIdx.x;   // 0 .. 1024*32
    const int row = idx >> 5, c = idx & 31;
    out[idx] = (c < 8) ? f2bf(in[row * 8 + c]) : (ushort)0;
}

// Precompute (once): w[f]=f2W@oW; u[f]=inW_v^T@w; d[f]=inb_v.w; cc[f]=ob.f2W+f2b
__global__ __launch_bounds__(256)
void precompute_kernel(const float* __restrict__ oW, const float* __restrict__ ob,
                       const float* __restrict__ f2W, const float* __restrict__ f2b,
                       const float* __restrict__ inW, const float* __restrict__ inb,
                       float* __restrict__ u, float* __restrict__ dconst,
                       float* __restrict__ ccv)
{
    __shared__ float wsh[256];
    const int f = blockIdx.x;
    const int tid = threadIdx.x;
    float s = 0.f;
    for (int i = 0; i < 256; ++i)
        s += f2W[f * 256 + i] * oW[(size_t)f * 65536 + (size_t)i * 256 + tid];
    wsh[tid] = s;
    __syncthreads();
    float su = 0.f;
    for (int n = 0; n < 256; ++n)
        su += wsh[n] * inW[(size_t)f * 768 * 256 + (size_t)(512 + n) * 256 + tid];
    u[f * 256 + tid] = su;
    if (tid == 0) {
        float dd = 0.f, cc = 0.f;
        for (int n = 0; n < 256; ++n) dd += wsh[n] * inb[f * 768 + 512 + n];
        for (int i = 0; i < 256; ++i) cc += ob[f * 256 + i] * f2W[f * 256 + i];
        dconst[f] = dd;
        ccv[f] = cc + f2b[f];
    }
}

// ---------------------------------------------------------------------------
// Persistent encoder v2: 256 WGs = 32 groups x 8 WGs. Group owns 32 batch rows;
// WG owns 32 hidden units; wave = gate. h-state crosses WGs via MALL (sc0 sc1);
// weights via normal cached loads (L2-resident, never invalidated); c in regs.
// Two 8-WG barriers per step. One launch for all 168 steps.
// ---------------------------------------------------------------------------
__global__ __launch_bounds__(256, 1)
void enc_persist2(const float* __restrict__ x,
                  const ushort* __restrict__ Whh0, const ushort* __restrict__ Wih0p,
                  const ushort* __restrict__ Wih1, const ushort* __restrict__ Whh1,
                  const float* __restrict__ bih0, const float* __restrict__ bhh0,
                  const float* __restrict__ bih1, const float* __restrict__ bhh1,
                  ushort* __restrict__ h0A, ushort* __restrict__ h0B,
                  ushort* __restrict__ h1A, ushort* __restrict__ h1B,
                  ushort* __restrict__ dh, float* __restrict__ dcb,
                  float* __restrict__ din, unsigned* __restrict__ bar)
{
    __shared__ ushort SA[32][264];
    __shared__ ushort SB[32][264];
    __shared__ ushort SC[32][264];
    __shared__ float pre[4][32][36];
    __shared__ ushort xL[32][32];

    const int tid = threadIdx.x;
    const int l = tid & 63;
    const int g = tid >> 6;            // wave index = gate (i,f,g,o)
    const int lr = l & 15, lq = l >> 4, lk = lq * 8;
    const int grp = blockIdx.x >> 3, wgi = blockIdx.x & 7;
    const int rowbase = grp * 32;
    const int ub = wgi * 32;           // hidden-unit base for this WG
    unsigned* cnt = bar + grp * 32;    // 128B-separated per-group counters

    // zero xL pad cols (8..31) once
    for (int e = tid; e < 32 * 32; e += 256) (&xL[0][0])[e] = 0;

    // per-thread c/h ownership: (row = tid>>3, units cu..cu+3)
    const int crow = tid >> 3;
    const int cu = (tid & 7) * 4;
    float c0v[4] = {0,0,0,0}, c1v[4] = {0,0,0,0};
    float h0v[4] = {0,0,0,0}, h1v[4] = {0,0,0,0};

    // biases per wave(gate) per n-frag
    float b0s[2], b1s[2];
#pragma unroll
    for (int n = 0; n < 2; ++n) {
        const int j = ub + n * 16 + lr;
        b0s[n] = bih0[g * H + j] + bhh0[g * H + j];
        b1s[n] = bih1[g * H + j] + bhh1[g * H + j];
    }

    unsigned bph = 0;
    __syncthreads();

    for (int t = 0; t < TIN; ++t) {
        const int p = t & 1;
        const ushort* h0r = p ? h0B : h0A;
        ushort*       h0w = p ? h0A : h0B;
        const ushort* h1r = p ? h1B : h1A;
        ushort*       h1w = p ? h1A : h1B;

        // ---- stage SA <- h0(prev) [MALL], xL <- x(t) [cached] ----
        {
            const ushort* src = h0r + rowbase * 256;
            f32x4 v0, v1, v2, v3;
            load_coh4(src + tid * 8, src + (tid + 256) * 8,
                      src + (tid + 512) * 8, src + (tid + 768) * 8, v0, v1, v2, v3);
            const int c16 = (tid & 31) * 8;
            *(f32x4*)&SA[tid >> 5][c16] = v0;
            *(f32x4*)&SA[(tid + 256) >> 5][c16] = v1;
            *(f32x4*)&SA[(tid + 512) >> 5][c16] = v2;
            *(f32x4*)&SA[(tid + 768) >> 5][c16] = v3;
            xL[tid >> 3][tid & 7] =
                f2bf(x[(size_t)(rowbase + (tid >> 3)) * XROW + t * Fh + (tid & 7)]);
        }
        __syncthreads();

        // ---- layer 0: gates = h0@Whh0^T + x@Wih0p^T (wave g computes gate g) ----
        {
            bf16x8 am[2][8], ax[2];
#pragma unroll
            for (int m = 0; m < 2; ++m) {
#pragma unroll
                for (int k = 0; k < 8; ++k)
                    am[m][k] = *(const bf16x8*)&SA[m * 16 + lr][k * 32 + lk];
                ax[m] = *(const bf16x8*)&xL[m * 16 + lr][lk];
            }
            f32x4 acc[2][2] = {};
#pragma unroll
            for (int n = 0; n < 2; ++n) {
                const ushort* wp = Whh0 + (size_t)(g * H + ub + n * 16 + lr) * H + lk;
#pragma unroll
                for (int k = 0; k < 8; ++k) {
                    const bf16x8 b8 = *(const bf16x8*)(wp + k * 32);
                    acc[0][n] = __builtin_amdgcn_mfma_f32_16x16x32_bf16(am[0][k], b8, acc[0][n], 0, 0, 0);
                    acc[1][n] = __builtin_amdgcn_mfma_f32_16x16x32_bf16(am[1][k], b8, acc[1][n], 0, 0, 0);
                }
                const bf16x8 bx = *(const bf16x8*)(Wih0p + (size_t)(g * H + ub + n * 16 + lr) * 32 + lk);
                acc[0][n] = __builtin_amdgcn_mfma_f32_16x16x32_bf16(ax[0], bx, acc[0][n], 0, 0, 0);
                acc[1][n] = __builtin_amdgcn_mfma_f32_16x16x32_bf16(ax[1], bx, acc[1][n], 0, 0, 0);
            }
#pragma unroll
            for (int m = 0; m < 2; ++m)
#pragma unroll
                for (int n = 0; n < 2; ++n)
#pragma unroll
                    for (int r = 0; r < 4; ++r)
                        pre[g][m * 16 + lq * 4 + r][n * 16 + lr] = acc[m][n][r] + b0s[n];
        }
        __syncthreads();

        // ---- c0/h0 update; write own h0 slice to MALL ----
        {
            const f32x4 pi = *(const f32x4*)&pre[0][crow][cu];
            const f32x4 pf = *(const f32x4*)&pre[1][crow][cu];
            const f32x4 pg = *(const f32x4*)&pre[2][crow][cu];
            const f32x4 po = *(const f32x4*)&pre[3][crow][cu];
#pragma unroll
            for (int j = 0; j < 4; ++j) {
                const float ig = sigmf(pi[j]);
                const float fg = sigmf(pf[j]);
                const float gg = tanhf_(pg[j]);
                const float og = sigmf(po[j]);
                c0v[j] = fg * c0v[j] + ig * gg;
                h0v[j] = og * tanhf_(c0v[j]);
            }
            uint2 hp;
            hp.x = (unsigned)f2bf(h0v[0]) | ((unsigned)f2bf(h0v[1]) << 16);
            hp.y = (unsigned)f2bf(h0v[2]) | ((unsigned)f2bf(h0v[3]) << 16);
            store_coh8B(h0w + (size_t)(rowbase + crow) * 256 + ub + cu, hp);
        }
        gbar2(cnt, ++bph * 8u);

        // ---- stage SB <- h0(new), SC <- h1(prev) [MALL] ----
        {
            const ushort* s0 = h0w + rowbase * 256;
            const ushort* s1 = h1r + rowbase * 256;
            f32x4 a0, a1, a2, a3, b0, b1, b2, b3;
            load_coh8(s0 + tid * 8, s0 + (tid + 256) * 8, s0 + (tid + 512) * 8, s0 + (tid + 768) * 8,
                      s1 + tid * 8, s1 + (tid + 256) * 8, s1 + (tid + 512) * 8, s1 + (tid + 768) * 8,
                      a0, a1, a2, a3, b0, b1, b2, b3);
            const int c16 = (tid & 31) * 8;
            *(f32x4*)&SB[tid >> 5][c16] = a0;
            *(f32x4*)&SB[(tid + 256) >> 5][c16] = a1;
            *(f32x4*)&SB[(tid + 512) >> 5][c16] = a2;
            *(f32x4*)&SB[(tid + 768) >> 5][c16] = a3;
            *(f32x4*)&SC[tid >> 5][c16] = b0;
            *(f32x4*)&SC[(tid + 256) >> 5][c16] = b1;
            *(f32x4*)&SC[(tid + 512) >> 5][c16] = b2;
            *(f32x4*)&SC[(tid + 768) >> 5][c16] = b3;
        }
        __syncthreads();

        // ---- layer 1: gates = h0_new@Wih1^T + h1@Whh1^T ----
        {
            bf16x8 an[2][8], ah[2][8];
#pragma unroll
            for (int m = 0; m < 2; ++m)
#pragma unroll
                for (int k = 0; k < 8; ++k) {
                    an[m][k] = *(const bf16x8*)&SB[m * 16 + lr][k * 32 + lk];
                    ah[m][k] = *(const bf16x8*)&SC[m * 16 + lr][k * 32 + lk];
                }
            f32x4 acc[2][2] = {};
#pragma unroll
            for (int n = 0; n < 2; ++n) {
                const ushort* w1 = Wih1 + (size_t)(g * H + ub + n * 16 + lr) * H + lk;
                const ushort* w2 = Whh1 + (size_t)(g * H + ub + n * 16 + lr) * H + lk;
#pragma unroll
                for (int k = 0; k < 8; ++k) {
                    const bf16x8 b1 = *(const bf16x8*)(w1 + k * 32);
                    acc[0][n] = __builtin_amdgcn_mfma_f32_16x16x32_bf16(an[0][k], b1, acc[0][n], 0, 0, 0);
                    acc[1][n] = __builtin_amdgcn_mfma_f32_16x16x32_bf16(an[1][k], b1, acc[1][n], 0, 0, 0);
                    const bf16x8 b2 = *(const bf16x8*)(w2 + k * 32);
                    acc[0][n] = __builtin_amdgcn_mfma_f32_16x16x32_bf16(ah[0][k], b2, acc[0][n], 0, 0, 0);
                    acc[1][n] = __builtin_amdgcn_mfma_f32_16x16x32_bf16(ah[1][k], b2, acc[1][n], 0, 0, 0);
                }
            }
#pragma unroll
            for (int m = 0; m < 2; ++m)
#pragma unroll
                for (int n = 0; n < 2; ++n)
#pragma unroll
                    for (int r = 0; r < 4; ++r)
                        pre[g][m * 16 + lq * 4 + r][n * 16 + lr] = acc[m][n][r] + b1s[n];
        }
        __syncthreads();

        // ---- c1/h1 update; write own h1 slice to MALL ----
        {
            const f32x4 pi = *(const f32x4*)&pre[0][crow][cu];
            const f32x4 pf = *(const f32x4*)&pre[1][crow][cu];
            const f32x4 pg = *(const f32x4*)&pre[2][crow][cu];
            const f32x4 po = *(const f32x4*)&pre[3][crow][cu];
#pragma unroll
            for (int j = 0; j < 4; ++j) {
                const float ig = sigmf(pi[j]);
                const float fg = sigmf(pf[j]);
                const float gg = tanhf_(pg[j]);
                const float og = sigmf(po[j]);
                c1v[j] = fg * c1v[j] + ig * gg;
                h1v[j] = og * tanhf_(c1v[j]);
            }
            uint2 hp;
            hp.x = (unsigned)f2bf(h1v[0]) | ((unsigned)f2bf(h1v[1]) << 16);
            hp.y = (unsigned)f2bf(h1v[2]) | ((unsigned)f2bf(h1v[3]) << 16);
            store_coh8B(h1w + (size_t)(rowbase + crow) * 256 + ub + cu, hp);
        }
        gbar2(cnt, ++bph * 8u);
    }

    // ---- tail: decoder init from registers (normal stores; kernel boundary
    //      flush makes them visible to the decoder dispatches) ----
    {
        uint2 hm2;
        float cm[4];
        float hm[4];
#pragma unroll
        for (int j = 0; j < 4; ++j) {
            hm[j] = 0.5f * (h0v[j] + h1v[j]);
            cm[j] = 0.5f * (c0v[j] + c1v[j]);
        }
        hm2.x = (unsigned)f2bf(hm[0]) | ((unsigned)f2bf(hm[1]) << 16);
        hm2.y = (unsigned)f2bf(hm[2]) | ((unsigned)f2bf(hm[3]) << 16);
        const size_t idx = (size_t)(rowbase + crow) * 256 + ub + cu;
#pragma unroll
        for (int f = 0; f < Fh; ++f) {
            *(uint2*)&dh[f * BH + idx] = hm2;
            float4 c4; c4.x = cm[0]; c4.y = cm[1]; c4.z = cm[2]; c4.w = cm[3];
            *(float4*)&dcb[f * BH + idx] = c4;
        }
        if (wgi == 0) {
            const int r = tid >> 3, fc = tid & 7;
            din[(rowbase + r) * Fh + fc] =
                x[(size_t)(rowbase + r) * XROW + (TIN - 1) * Fh + fc];
        }
    }
}

// ---------------------------------------------------------------------------
// Fused decoder step (verbatim from round 5): [attn(t-1)] + [dec(t)].
// ---------------------------------------------------------------------------
template<int DO_ATTN, int DO_DEC>
__global__ __launch_bounds__(256, 1)
void dec_step(const ushort* __restrict__ qprev, const ushort* __restrict__ kprev,
              const float* __restrict__ vwprev,
              ushort* __restrict__ qcur, ushort* __restrict__ kcur,
              float* __restrict__ vwcur,
              ushort* __restrict__ dhg, float* __restrict__ dcg,
              const ushort* __restrict__ Whh, const float* __restrict__ Wih,
              const float* __restrict__ bih, const float* __restrict__ bhh,
              const ushort* __restrict__ f1Wb, const float* __restrict__ f1b,
              const ushort* __restrict__ inWb, const float* __restrict__ inb,
              const float* __restrict__ u, const float* __restrict__ dconst,
              const float* __restrict__ ccv, const float* __restrict__ din0,
              float* __restrict__ out, int t)
{
    __shared__ ushort h2s[32][264];
    __shared__ ushort as[32][264];
    __shared__ float dinL[32];
    __shared__ float tri[4][2][16][3];
    const int bid = blockIdx.x;
    const int f = bid & 7, mb = bid >> 3;
    const int m0 = mb * 32;
    const int tid = threadIdx.x;
    const int l = tid & 63, w = tid >> 6;
    const int lr = l & 15, lq = l >> 4, lk = lq * 8;

    if (DO_ATTN) {
        bf16x8 qf[2][8];
#pragma unroll
        for (int m = 0; m < 2; ++m)
#pragma unroll
            for (int k = 0; k < 8; ++k)
                qf[m][k] = *(const bf16x8*)(qprev + ((size_t)f * Bsz + m0 + m * 16 + lr) * H + k * 32 + lk);
        float mM0 = -1e30f, lS0 = 0.f, oS0 = 0.f;
        float mM1 = -1e30f, lS1 = 0.f, oS1 = 0.f;
        const int kb0 = w * 256;
        for (int kf = 0; kf < 16; ++kf) {
            const int kb = kb0 + kf * 16;
            f32x4 acc0 = {}, acc1 = {};
#pragma unroll
            for (int k = 0; k < 8; ++k) {
                const bf16x8 k8 = *(const bf16x8*)(kprev + ((size_t)f * Bsz + kb + lr) * H + k * 32 + lk);
                acc0 = __builtin_amdgcn_mfma_f32_16x16x32_bf16(k8, qf[0][k], acc0, 0, 0, 0);
                acc1 = __builtin_amdgcn_mfma_f32_16x16x32_bf16(k8, qf[1][k], acc1, 0, 0, 0);
            }
            const float4 v4 = *(const float4*)(vwprev + f * Bsz + kb + lq * 4);
            {
                const float mx = fmaxf(fmaxf(acc0[0], acc0[1]), fmaxf(acc0[2], acc0[3]));
                const float mn = fmaxf(mM0, mx);
                const float sc = __expf(mM0 - mn);
                const float e0 = __expf(acc0[0] - mn), e1 = __expf(acc0[1] - mn);
                const float e2 = __expf(acc0[2] - mn), e3 = __expf(acc0[3] - mn);
                lS0 = lS0 * sc + (e0 + e1 + e2 + e3);
                oS0 = oS0 * sc + (e0 * v4.x + e1 * v4.y + e2 * v4.z + e3 * v4.w);
                mM0 = mn;
            }
            {
                const float mx = fmaxf(fmaxf(acc1[0], acc1[1]), fmaxf(acc1[2], acc1[3]));
                const float mn = fmaxf(mM1, mx);
                const float sc = __expf(mM1 - mn);
                const float e0 = __expf(acc1[0] - mn), e1 = __expf(acc1[1] - mn);
                const float e2 = __expf(acc1[2] - mn), e3 = __expf(acc1[3] - mn);
                lS1 = lS1 * sc + (e0 + e1 + e2 + e3);
                oS1 = oS1 * sc + (e0 * v4.x + e1 * v4.y + e2 * v4.z + e3 * v4.w);
                mM1 = mn;
            }
        }
#pragma unroll
        for (int d = 16; d < 64; d <<= 1) {
            {
                const float m2 = __shfl_xor(mM0, d), l2 = __shfl_xor(lS0, d), o2 = __shfl_xor(oS0, d);
                const float mn = fmaxf(mM0, m2);
                const float sa = __expf(mM0 - mn), sb = __expf(m2 - mn);
                lS0 = lS0 * sa + l2 * sb; oS0 = oS0 * sa + o2 * sb; mM0 = mn;
            }
            {
                const float m2 = __shfl_xor(mM1, d), l2 = __shfl_xor(lS1, d), o2 = __shfl_xor(oS1, d);
                const float mn = fmaxf(mM1, m2);
                const float sa = __expf(mM1 - mn), sb = __expf(m2 - mn);
                lS1 = lS1 * sa + l2 * sb; oS1 = oS1 * sa + o2 * sb; mM1 = mn;
            }
        }
        if (l < 16) {
            tri[w][0][l][0] = mM0; tri[w][0][l][1] = lS0; tri[w][0][l][2] = oS0;
            tri[w][1][l][0] = mM1; tri[w][1][l][1] = lS1; tri[w][1][l][2] = oS1;
        }
        __syncthreads();
        if (tid < 32) {
            const int m = tid >> 4, qr = tid & 15;
            float M = tri[0][m][qr][0], L = tri[0][m][qr][1], O = tri[0][m][qr][2];
#pragma unroll
            for (int ww = 1; ww < 4; ++ww) {
                const float m2 = tri[ww][m][qr][0], l2 = tri[ww][m][qr][1], o2 = tri[ww][m][qr][2];
                const float mn = fmaxf(M, m2);
                const float sa = __expf(M - mn), sb = __expf(m2 - mn);
                L = L * sa + l2 * sb; O = O * sa + o2 * sb; M = mn;
            }
            float val = __fdividef(O, L) + ccv[f];
            val = (val > 0.f) ? val : 0.01f * val;
            const int b = m0 + m * 16 + qr;
            out[(size_t)b * (TOUT * Fh) + (size_t)(t - 1) * Fh + f] = val;
            dinL[m * 16 + qr] = val;
        }
        __syncthreads();
    }

    if (DO_DEC) {
        float bsum[4][4], wxr[4][4];
#pragma unroll
        for (int jt = 0; jt < 4; ++jt)
#pragma unroll
            for (int g = 0; g < 4; ++g) {
                const int j = w * 64 + jt * 16 + lr;
                bsum[jt][g] = bih[f * H4 + g * H + j] + bhh[f * H4 + g * H + j];
                wxr[jt][g] = Wih[f * H4 + g * H + j];
            }
        bf16x8 af[2][8];
#pragma unroll
        for (int m = 0; m < 2; ++m)
#pragma unroll
            for (int k = 0; k < 8; ++k)
                af[m][k] = *(const bf16x8*)(dhg + ((size_t)f * Bsz + m0 + m * 16 + lr) * H + k * 32 + lk);
        __syncthreads();
        const ushort* Wb = Whh + (size_t)f * (H4 * H);
#pragma unroll 1
        for (int jt = 0; jt < 4; ++jt) {
            const int jb = w * 64 + jt * 16;
            f32x4 acc[2][4] = {};
#pragma unroll
            for (int k = 0; k < 8; ++k)
#pragma unroll
                for (int g = 0; g < 4; ++g) {
                    const bf16x8 bf = *(const bf16x8*)(Wb + (size_t)(g * H + jb + lr) * H + k * 32 + lk);
                    acc[0][g] = __builtin_amdgcn_mfma_f32_16x16x32_bf16(af[0][k], bf, acc[0][g], 0, 0, 0);
                    acc[1][g] = __builtin_amdgcn_mfma_f32_16x16x32_bf16(af[1][k], bf, acc[1][g], 0, 0, 0);
                }
#pragma unroll
            for (int m = 0; m < 2; ++m)
#pragma unroll
                for (int r = 0; r < 4; ++r) {
                    const int row = m * 16 + lq * 4 + r;
                    const float xi = DO_ATTN ? dinL[row] : din0[(m0 + row) * Fh + f];
                    const float ig = sigmf(acc[m][0][r] + bsum[jt][0] + xi * wxr[jt][0]);
                    const float fg = sigmf(acc[m][1][r] + bsum[jt][1] + xi * wxr[jt][1]);
                    const float gg = tanhf_(acc[m][2][r] + bsum[jt][2] + xi * wxr[jt][2]);
                    const float og = sigmf(acc[m][3][r] + bsum[jt][3] + xi * wxr[jt][3]);
                    const size_t off = ((size_t)f * Bsz + m0 + row) * H + jb + lr;
                    const float cn = fg * dcg[off] + ig * gg;
                    dcg[off] = cn;
                    const ushort hb = f2bf(og * tanhf_(cn));
                    dhg[off] = hb;
                    h2s[row][jb + lr] = hb;
                }
        }
        __syncthreads();
        // ---- fc1 ----
        bf16x8 a2[2][8];
#pragma unroll
        for (int m = 0; m < 2; ++m)
#pragma unroll
            for (int k = 0; k < 8; ++k)
                a2[m][k] = *(const bf16x8*)&h2s[m * 16 + lr][k * 32 + lk];
        const ushort* Wf = f1Wb + (size_t)f * H * H;
#pragma unroll 1
        for (int nt = 0; nt < 4; ++nt) {
            const int n0 = w * 64 + nt * 16;
            f32x4 acc0 = {}, acc1 = {};
#pragma unroll
            for (int k = 0; k < 8; ++k) {
                const bf16x8 b8 = *(const bf16x8*)(Wf + (size_t)(n0 + lr) * H + k * 32 + lk);
                acc0 = __builtin_amdgcn_mfma_f32_16x16x32_bf16(a2[0][k], b8, acc0, 0, 0, 0);
                acc1 = __builtin_amdgcn_mfma_f32_16x16x32_bf16(a2[1][k], b8, acc1, 0, 0, 0);
            }
            const float bv = f1b[f * H + n0 + lr];
#pragma unroll
            for (int r = 0; r < 4; ++r) {
                float v0 = acc0[r] + bv; v0 = (v0 > 0.f) ? v0 : 0.01f * v0;
                as[lq * 4 + r][n0 + lr] = f2bf(v0);
                float v1 = acc1[r] + bv; v1 = (v1 > 0.f) ? v1 : 0.01f * v1;
                as[16 + lq * 4 + r][n0 + lr] = f2bf(v1);
            }
        }
        __syncthreads();
        // ---- q,k projection ----
        bf16x8 a3[2][8];
#pragma unroll
        for (int m = 0; m < 2; ++m)
#pragma unroll
            for (int k = 0; k < 8; ++k)
                a3[m][k] = *(const bf16x8*)&as[m * 16 + lr][k * 32 + lk];
        const ushort* Wi = inWb + (size_t)f * 768 * H;
#pragma unroll 1
        for (int nt = 0; nt < 8; ++nt) {
            const int n0 = w * 128 + nt * 16;
            f32x4 acc0 = {}, acc1 = {};
#pragma unroll
            for (int k = 0; k < 8; ++k) {
                const bf16x8 b8 = *(const bf16x8*)(Wi + (size_t)(n0 + lr) * H + k * 32 + lk);
                acc0 = __builtin_amdgcn_mfma_f32_16x16x32_bf16(a3[0][k], b8, acc0, 0, 0, 0);
                acc1 = __builtin_amdgcn_mfma_f32_16x16x32_bf16(a3[1][k], b8, acc1, 0, 0, 0);
            }
            const float bv = inb[f * 768 + n0 + lr];
#pragma unroll
            for (int m = 0; m < 2; ++m)
#pragma unroll
                for (int r = 0; r < 4; ++r) {
                    const float v = (m ? acc1[r] : acc0[r]) + bv;
                    const int mrow = m0 + m * 16 + lq * 4 + r;
                    if (n0 < 256)
                        qcur[((size_t)f * Bsz + mrow) * H + n0 + lr] = f2bf(v * 0.0625f);
                    else
                        kcur[((size_t)f * Bsz + mrow) * H + n0 - 256 + lr] = f2bf(v);
                }
        }
        // ---- vw[m] = a[m].u[f] + d[f] ----
        const float4 u4 = *(const float4*)(u + f * H + l * 4);
#pragma unroll 1
        for (int rr = 0; rr < 8; ++rr) {
            const int mloc = w * 8 + rr;
            const ushort4 a4 = *(const ushort4*)&as[mloc][l * 4];
            float s = bf2f(a4.x) * u4.x + bf2f(a4.y) * u4.y
                    + bf2f(a4.z) * u4.z + bf2f(a4.w) * u4.w;
#pragma unroll
            for (int d = 1; d < 64; d <<= 1) s += __shfl_xor(s, d);
            if (l == 0) vwcur[f * Bsz + m0 + mloc] = s + dconst[f];
        }
    }
}

extern "C" void kernel_launch(void* const* d_in, const int* in_sizes, int n_in,
                              void* d_out, int out_size, void* d_ws, size_t ws_size,
                              hipStream_t stream)
{
    const float* x     = (const float*)d_in[0];
    const float* eWih0 = (const float*)d_in[1];
    const float* eWhh0 = (const float*)d_in[2];
    const float* ebih0 = (const float*)d_in[3];
    const float* ebhh0 = (const float*)d_in[4];
    const float* eWih1 = (const float*)d_in[5];
    const float* eWhh1 = (const float*)d_in[6];
    const float* ebih1 = (const float*)d_in[7];
    const float* ebhh1 = (const float*)d_in[8];
    const float* dWih  = (const float*)d_in[9];
    const float* dWhh  = (const float*)d_in[10];
    const float* dbih  = (const float*)d_in[11];
    const float* dbhh  = (const float*)d_in[12];
    const float* f1W   = (const float*)d_in[13];
    const float* f1b   = (const float*)d_in[14];
    const float* inW   = (const float*)d_in[15];
    const float* inb   = (const float*)d_in[16];
    const float* oW    = (const float*)d_in[17];
    const float* ob    = (const float*)d_in[18];
    const float* f2W   = (const float*)d_in[19];
    const float* f2b   = (const float*)d_in[20];
    float* out = (float*)d_out;

    // ---- workspace ----
    char* base = (char*)d_ws;
    size_t o = 0;
    auto alloc = [&](size_t bytes) { void* p = base + o; o += (bytes + 255) & ~(size_t)255; return p; };
    // encoder h state (MALL-coherent traffic) — h0A,h1A first (zeroed together)
    ushort* h0A = (ushort*)alloc(BH * 2);
    ushort* h1A = (ushort*)alloc(BH * 2);
    ushort* h0B = (ushort*)alloc(BH * 2);
    ushort* h1B = (ushort*)alloc(BH * 2);
    unsigned* bar = (unsigned*)alloc(32 * 32 * 4);
    ushort* qb[2]; ushort* kb[2]; float* vw[2];
    qb[0] = (ushort*)alloc(8 * BH * 2);
    qb[1] = (ushort*)alloc(8 * BH * 2);
    kb[0] = (ushort*)alloc(8 * BH * 2);
    kb[1] = (ushort*)alloc(8 * BH * 2);
    vw[0] = (float*)alloc((size_t)Fh * Bsz * 4);
    vw[1] = (float*)alloc((size_t)Fh * Bsz * 4);
    ushort* dhg  = (ushort*)alloc(8 * BH * 2);
    float*  dcg  = (float*)alloc(8 * BH * 4);
    float*  din0 = (float*)alloc((size_t)Bsz * Fh * 4);
    float*  ubuf = (float*)alloc((size_t)Fh * H * 4);
    float*  dbuf = (float*)alloc(Fh * 4);
    float*  ccb  = (float*)alloc(Fh * 4);
    ushort* wWhh0 = (ushort*)alloc((size_t)H4 * H * 2);
    ushort* wWih0p= (ushort*)alloc((size_t)H4 * 32 * 2);
    ushort* wWih1 = (ushort*)alloc((size_t)H4 * H * 2);
    ushort* wWhh1 = (ushort*)alloc((size_t)H4 * H * 2);
    ushort* wdWhh = (ushort*)alloc((size_t)8 * H4 * H * 2);
    ushort* wf1W  = (ushort*)alloc((size_t)8 * H * H * 2);
    ushort* winW  = (ushort*)alloc((size_t)8 * 768 * H * 2);

    const dim3 blk(256);

    // zero h0A,h1A (parity-0 initial state) + barrier counters
    hipMemsetAsync(d_ws, 0, BH * 2 * 2, stream);
    hipMemsetAsync(bar, 0, 32 * 32 * 4, stream);

    // ---- weight casts + precompute ----
    cast_f32_bf16<<<dim3(512), blk, 0, stream>>>(eWhh0, wWhh0, H4 * H);
    cast_f32_bf16<<<dim3(512), blk, 0, stream>>>(eWih1, wWih1, H4 * H);
    cast_f32_bf16<<<dim3(512), blk, 0, stream>>>(eWhh1, wWhh1, H4 * H);
    cast_pad_wih0<<<dim3(128), blk, 0, stream>>>(eWih0, wWih0p);
    cast_f32_bf16<<<dim3(1024), blk, 0, stream>>>(dWhh, wdWhh, 8 * H4 * H);
    cast_f32_bf16<<<dim3(512), blk, 0, stream>>>(f1W, wf1W, 8 * H * H);
    cast_f32_bf16<<<dim3(1024), blk, 0, stream>>>(inW, winW, 8 * 768 * H);
    precompute_kernel<<<dim3(8), blk, 0, stream>>>(oW, ob, f2W, f2b, inW, inb,
                                                   ubuf, dbuf, ccb);

    // ---- encoder: ONE persistent launch, MALL-coherent h + 8-WG barriers ----
    enc_persist2<<<dim3(256), blk, 0, stream>>>(
        x, wWhh0, wWih0p, wWih1, wWhh1, ebih0, ebhh0, ebih1, ebhh1,
        h0A, h0B, h1A, h1B, dhg, dcg, din0, bar);

    // ---- decoder: 25 launches ----
    dec_step<0, 1><<<dim3(256), blk, 0, stream>>>(
        qb[1], kb[1], vw[1], qb[0], kb[0], vw[0], dhg, dcg,
        wdWhh, dWih, dbih, dbhh, wf1W, f1b, winW, inb,
        ubuf, dbuf, ccb, din0, out, 0);
    for (int t = 1; t < TOUT; ++t) {
        const int pp = (t - 1) & 1, pc = t & 1;
        dec_step<1, 1><<<dim3(256), blk, 0, stream>>>(
            qb[pp], kb[pp], vw[pp], qb[pc], kb[pc], vw[pc], dhg, dcg,
            wdWhh, dWih, dbih, dbhh, wf1W, f1b, winW, inb,
            ubuf, dbuf, ccb, din0, out, t);
    }
    dec_step<1, 0><<<dim3(256), blk, 0, stream>>>(
        qb[1], kb[1], vw[1], qb[0], kb[0], vw[0], dhg, dcg,
        wdWhh, dWih, dbih, dbhh, wf1W, f1b, winW, inb,
        ubuf, dbuf, ccb, din0, out, TOUT);

    (void)in_sizes; (void)n_in; (void)out_size; (void)ws_size;
}